// Round 2
// baseline (918.703 us; speedup 1.0000x reference)
//
#include <hip/hip_runtime.h>

#define N 6144
#define E 196608
#define EN (E + N)      // 202752
#define LGAT 10

typedef unsigned int u32;

// order-preserving float<->uint for atomicMax/Min on floats (incl. negatives)
__device__ __forceinline__ u32 f2key(float f) {
    u32 u = __float_as_uint(f);
    return (u & 0x80000000u) ? ~u : (u | 0x80000000u);
}
__device__ __forceinline__ float key2f(u32 k) {
    u32 u = (k & 0x80000000u) ? (k & 0x7FFFFFFFu) : ~k;
    return __uint_as_float(u);
}

struct P {
    // fp32 inputs
    const float *x, *mask, *gat_W, *gat_asrc, *gat_adst, *gat_b;
    const float *in_w, *in_b, *out_w, *out_b;
    const float *Wq, *bq, *Wk, *bk, *Wv, *bv, *Wsk, *bsk;
    const float *W1, *b1, *W2, *b2, *W3, *b3, *cW, *cb;
    const int *src, *dst;
    // fp32 workspace
    float *xp, *ssrc, *sdst, *zseg, *agg, *ebuf, *qkv, *qkv2, *h2, *h3, *numden;
    float *a1pre, *a2buf, *sumres;
    u32 *mkey, *kmaxk, *kmink;
    float *out;
};

// ---- tiny accumulator inits ----------------------------------------------
__global__ void k_init(P p) {
    int t = threadIdx.x;
    if (t < 3) p.kmaxk[t] = 0u;
    else if (t < 6) p.kmink[t - 3] = 0xFFFFFFFFu;
    else if (t < 22) p.a1pre[t - 6] = 0.f;
    else if (t == 22) p.sumres[0] = 0.f;
}

// ---- GAT node kernel: finalize prev layer, compute xp/ssrc/sdst, init segs
__global__ void k_gat_node(P p, int l) {
    int n = blockIdx.x * 256 + threadIdx.x;
    if (n >= N) return;
    float h0, h1, h2;
    if (l == 0) {
        h0 = p.x[n * 3 + 0]; h1 = p.x[n * 3 + 1]; h2 = p.x[n * 3 + 2];
    } else {
        float z = p.zseg[n] + 1e-16f;
        int lb = l - 1;
        h0 = fmaxf(p.agg[n * 3 + 0] / z + p.gat_b[lb * 3 + 0], 0.f);
        h1 = fmaxf(p.agg[n * 3 + 1] / z + p.gat_b[lb * 3 + 1], 0.f);
        h2 = fmaxf(p.agg[n * 3 + 2] / z + p.gat_b[lb * 3 + 2], 0.f);
    }
    const float* W = p.gat_W + l * 9;
    float xp0 = h0 * W[0] + h1 * W[3] + h2 * W[6];
    float xp1 = h0 * W[1] + h1 * W[4] + h2 * W[7];
    float xp2 = h0 * W[2] + h1 * W[5] + h2 * W[8];
    p.xp[n * 3 + 0] = xp0; p.xp[n * 3 + 1] = xp1; p.xp[n * 3 + 2] = xp2;
    const float* as = p.gat_asrc + l * 3;
    const float* ad = p.gat_adst + l * 3;
    p.ssrc[n] = xp0 * as[0] + xp1 * as[1] + xp2 * as[2];
    p.sdst[n] = xp0 * ad[0] + xp1 * ad[1] + xp2 * ad[2];
    p.mkey[n] = 0u;
    p.zseg[n] = 0.f;
    p.agg[n * 3 + 0] = 0.f; p.agg[n * 3 + 1] = 0.f; p.agg[n * 3 + 2] = 0.f;
}

// ---- GAT edge pass 1: leaky_relu score + segment max ---------------------
__global__ void k_edge_max(P p) {
    int e = blockIdx.x * 256 + threadIdx.x;
    if (e >= EN) return;
    int s = (e < E) ? p.src[e] : (e - E);
    int d = (e < E) ? p.dst[e] : (e - E);
    float v = p.ssrc[s] + p.sdst[d];
    v = (v >= 0.f) ? v : 0.2f * v;
    p.ebuf[e] = v;
    atomicMax(&p.mkey[d], f2key(v));
}

// ---- GAT edge pass 2: exp + segment sum + weighted aggregation -----------
__global__ void k_edge_sum(P p) {
    int e = blockIdx.x * 256 + threadIdx.x;
    if (e >= EN) return;
    int s = (e < E) ? p.src[e] : (e - E);
    int d = (e < E) ? p.dst[e] : (e - E);
    float m = key2f(p.mkey[d]);
    float w = __expf(p.ebuf[e] - m);
    atomicAdd(&p.zseg[d], w);
    atomicAdd(&p.agg[d * 3 + 0], w * p.xp[s * 3 + 0]);
    atomicAdd(&p.agg[d * 3 + 1], w * p.xp[s * 3 + 1]);
    atomicAdd(&p.agg[d * 3 + 2], w * p.xp[s * 3 + 2]);
}

// ---- finalize GAT layer 9 (no relu) + qkv projection + k min/max ---------
__global__ void k_qkv(P p) {
    int n = blockIdx.x * 256 + threadIdx.x;   // grid exactly covers N
    float z = p.zseg[n] + 1e-16f;
    float h0 = p.agg[n * 3 + 0] / z + p.gat_b[27];
    float h1 = p.agg[n * 3 + 1] / z + p.gat_b[28];
    float h2 = p.agg[n * 3 + 2] / z + p.gat_b[29];
    float kk[3];
    #pragma unroll
    for (int j = 0; j < 9; ++j) {
        float v = h0 * p.in_w[j * 3 + 0] + h1 * p.in_w[j * 3 + 1] +
                  h2 * p.in_w[j * 3 + 2] + p.in_b[j];
        p.qkv[n * 9 + j] = v;
        if (j >= 3 && j < 6) kk[j - 3] = v;
    }
    // zero the attention num/den accumulators
    #pragma unroll
    for (int j = 0; j < 6; ++j) p.numden[n * 6 + j] = 0.f;
    #pragma unroll
    for (int hh = 0; hh < 3; ++hh) {
        float mx = kk[hh], mn = kk[hh];
        #pragma unroll
        for (int o = 32; o; o >>= 1) {
            mx = fmaxf(mx, __shfl_xor(mx, o));
            mn = fminf(mn, __shfl_xor(mn, o));
        }
        if ((threadIdx.x & 63) == 0) {
            atomicMax(&p.kmaxk[hh], f2key(mx));
            atomicMin(&p.kmink[hh], f2key(mn));
        }
    }
}

// ---- MHA: rank-1 attention, chunked over m, exact max via kmax/kmin ------
#define MCH 384   // 6144/16
__global__ void k_att_partial(P p) {
    __shared__ float kv[MCH * 6];
    int tid = threadIdx.x;
    int chunk = blockIdx.y;
    int mbase = chunk * MCH;
    for (int i = tid; i < MCH * 6; i += 256) {
        int mm = i / 6, r = i - mm * 6;       // r 0..2 -> k[h], 3..5 -> v[h]
        kv[i] = p.qkv[(mbase + mm) * 9 + 3 + r];
    }
    __syncthreads();
    int n = blockIdx.x * 256 + tid;
    float q0 = p.qkv[n * 9 + 0], q1 = p.qkv[n * 9 + 1], q2 = p.qkv[n * 9 + 2];
    float kmx0 = key2f(p.kmaxk[0]), kmx1 = key2f(p.kmaxk[1]), kmx2 = key2f(p.kmaxk[2]);
    float kmn0 = key2f(p.kmink[0]), kmn1 = key2f(p.kmink[1]), kmn2 = key2f(p.kmink[2]);
    // exact row max of q*k over ALL m: q>=0 -> q*kmax else q*kmin
    float M0 = (q0 >= 0.f) ? q0 * kmx0 : q0 * kmn0;
    float M1 = (q1 >= 0.f) ? q1 * kmx1 : q1 * kmn1;
    float M2 = (q2 >= 0.f) ? q2 * kmx2 : q2 * kmn2;
    float num0 = 0, den0 = 0, num1 = 0, den1 = 0, num2 = 0, den2 = 0;
    for (int mm = 0; mm < MCH; ++mm) {
        float k0 = kv[mm * 6 + 0], k1 = kv[mm * 6 + 1], k2 = kv[mm * 6 + 2];
        float v0 = kv[mm * 6 + 3], v1 = kv[mm * 6 + 4], v2 = kv[mm * 6 + 5];
        float t0 = __expf(q0 * k0 - M0); den0 += t0; num0 += t0 * v0;
        float t1 = __expf(q1 * k1 - M1); den1 += t1; num1 += t1 * v1;
        float t2 = __expf(q2 * k2 - M2); den2 += t2; num2 += t2 * v2;
    }
    float* nd = p.numden + n * 6;
    atomicAdd(&nd[0], num0); atomicAdd(&nd[1], den0);
    atomicAdd(&nd[2], num1); atomicAdd(&nd[3], den1);
    atomicAdd(&nd[4], num2); atomicAdd(&nd[5], den2);
}

// ---- MHA reduce + out-proj + TC q2/k2/v2 + seg-init ----------------------
__global__ void k_att_reduce(P p) {
    int n = blockIdx.x * 256 + threadIdx.x;
    float o[3];
    #pragma unroll
    for (int hh = 0; hh < 3; ++hh)
        o[hh] = p.numden[n * 6 + hh * 2] / p.numden[n * 6 + hh * 2 + 1];
    float h2v[3];
    #pragma unroll
    for (int c = 0; c < 3; ++c) {
        h2v[c] = p.out_b[c] + o[0] * p.out_w[c * 3 + 0] +
                 o[1] * p.out_w[c * 3 + 1] + o[2] * p.out_w[c * 3 + 2];
        p.h2[n * 3 + c] = h2v[c];
    }
    #pragma unroll
    for (int c = 0; c < 3; ++c) {
        float q2 = p.bq[c] + h2v[0] * p.Wq[c] + h2v[1] * p.Wq[3 + c] + h2v[2] * p.Wq[6 + c];
        float k2 = p.bk[c] + h2v[0] * p.Wk[c] + h2v[1] * p.Wk[3 + c] + h2v[2] * p.Wk[6 + c];
        float v2 = p.bv[c] + h2v[0] * p.Wv[c] + h2v[1] * p.Wv[3 + c] + h2v[2] * p.Wv[6 + c];
        p.qkv2[n * 9 + c] = q2;
        p.qkv2[n * 9 + 3 + c] = k2;
        p.qkv2[n * 9 + 6 + c] = v2;
    }
    p.mkey[n] = 0u;
    p.zseg[n] = 0.f;
    p.agg[n * 3 + 0] = 0.f; p.agg[n * 3 + 1] = 0.f; p.agg[n * 3 + 2] = 0.f;
}

// ---- TC edge pass 1 ------------------------------------------------------
__global__ void k_tc_max(P p) {
    int e = blockIdx.x * 256 + threadIdx.x;
    if (e >= EN) return;
    int s = (e < E) ? p.src[e] : (e - E);
    int d = (e < E) ? p.dst[e] : (e - E);
    float lg = (p.qkv2[d * 9 + 0] * p.qkv2[s * 9 + 3] +
                p.qkv2[d * 9 + 1] * p.qkv2[s * 9 + 4] +
                p.qkv2[d * 9 + 2] * p.qkv2[s * 9 + 5]) * 0.57735026919f;
    p.ebuf[e] = lg;
    atomicMax(&p.mkey[d], f2key(lg));
}

// ---- TC edge pass 2 ------------------------------------------------------
__global__ void k_tc_sum(P p) {
    int e = blockIdx.x * 256 + threadIdx.x;
    if (e >= EN) return;
    int s = (e < E) ? p.src[e] : (e - E);
    int d = (e < E) ? p.dst[e] : (e - E);
    float m = key2f(p.mkey[d]);
    float w = __expf(p.ebuf[e] - m);
    atomicAdd(&p.zseg[d], w);
    atomicAdd(&p.agg[d * 3 + 0], w * p.qkv2[s * 9 + 6]);
    atomicAdd(&p.agg[d * 3 + 1], w * p.qkv2[s * 9 + 7]);
    atomicAdd(&p.agg[d * 3 + 2], w * p.qkv2[s * 9 + 8]);
}

// ---- TC finalize: h3 = agg/z + h2@Wskip + bskip --------------------------
__global__ void k_tc_final(P p) {
    int n = blockIdx.x * 256 + threadIdx.x;
    float z = p.zseg[n] + 1e-16f;
    float h0 = p.h2[n * 3 + 0], h1 = p.h2[n * 3 + 1], h2 = p.h2[n * 3 + 2];
    #pragma unroll
    for (int c = 0; c < 3; ++c) {
        float v = p.agg[n * 3 + c] / z + p.bsk[c] +
                  h0 * p.Wsk[c] + h1 * p.Wsk[3 + c] + h2 * p.Wsk[6 + c];
        p.h3[n * 3 + c] = v;
    }
}

// ---- MLP stage 1: flat(18432) @ W1(18432x16) -> a1pre[16] ----------------
__global__ void k_mlp1(P p) {
    int g = blockIdx.x * 256 + threadIdx.x;   // 6144 threads
    float acc[16];
    #pragma unroll
    for (int j = 0; j < 16; ++j) acc[j] = 0.f;
    for (int i = g; i < 3 * N; i += 6144) {
        float f = p.h3[i];
        const float* w = p.W1 + (size_t)i * 16;
        #pragma unroll
        for (int j = 0; j < 16; ++j) acc[j] += f * w[j];
    }
    #pragma unroll
    for (int o = 32; o; o >>= 1)
        #pragma unroll
        for (int j = 0; j < 16; ++j) acc[j] += __shfl_xor(acc[j], o);
    if ((threadIdx.x & 63) == 0)
        #pragma unroll
        for (int j = 0; j < 16; ++j) atomicAdd(&p.a1pre[j], acc[j]);
}

// ---- MLP stage 2: a1 -> a2 (tiny) ----------------------------------------
__global__ void k_mlp2(P p) {
    __shared__ float a1[16];
    int t = threadIdx.x;
    if (t < 16) a1[t] = fmaxf(p.a1pre[t] + p.b1[t], 0.f);
    __syncthreads();
    if (t < 32) {
        float acc = p.b2[t];
        #pragma unroll
        for (int i = 0; i < 16; ++i) acc += a1[i] * p.W2[i * 32 + t];
        p.a2buf[t] = fmaxf(acc, 0.f);
    }
}

// ---- MLP stage 3: results = a2 @ W3 + b3; out, mean ----------------------
__global__ void k_mlp3(P p) {
    __shared__ float a2[32];
    if (threadIdx.x < 32) a2[threadIdx.x] = p.a2buf[threadIdx.x];
    __syncthreads();
    int n = blockIdx.x * 256 + threadIdx.x;
    float acc = p.b3[n];
    #pragma unroll
    for (int j = 0; j < 32; ++j) acc += a2[j] * p.W3[(size_t)j * N + n];
    p.out[n] = acc * p.mask[n];
    float s = acc;
    #pragma unroll
    for (int o = 32; o; o >>= 1) s += __shfl_xor(s, o);
    if ((threadIdx.x & 63) == 0) atomicAdd(p.sumres, s);
}

// ---- value ---------------------------------------------------------------
__global__ void k_value(P p) {
    p.out[N] = p.cW[0] * (p.sumres[0] / (float)N) + p.cb[0];
}

extern "C" void kernel_launch(void* const* d_in, const int* in_sizes, int n_in,
                              void* d_out, int out_size, void* d_ws, size_t ws_size,
                              hipStream_t stream) {
    P p;
    p.x      = (const float*)d_in[0];
    p.mask   = (const float*)d_in[1];
    const int* ei = (const int*)d_in[2];
    p.src = ei; p.dst = ei + E;
    p.gat_W  = (const float*)d_in[3];
    p.gat_asrc = (const float*)d_in[4];
    p.gat_adst = (const float*)d_in[5];
    p.gat_b  = (const float*)d_in[6];
    p.in_w   = (const float*)d_in[7];
    p.in_b   = (const float*)d_in[8];
    p.out_w  = (const float*)d_in[9];
    p.out_b  = (const float*)d_in[10];
    p.Wq = (const float*)d_in[11]; p.bq = (const float*)d_in[12];
    p.Wk = (const float*)d_in[13]; p.bk = (const float*)d_in[14];
    p.Wv = (const float*)d_in[15]; p.bv = (const float*)d_in[16];
    p.Wsk = (const float*)d_in[17]; p.bsk = (const float*)d_in[18];
    p.W1 = (const float*)d_in[19]; p.b1 = (const float*)d_in[20];
    p.W2 = (const float*)d_in[21]; p.b2 = (const float*)d_in[22];
    p.W3 = (const float*)d_in[23]; p.b3 = (const float*)d_in[24];
    p.cW = (const float*)d_in[25]; p.cb = (const float*)d_in[26];

    float* ws = (float*)d_ws;
    p.xp     = ws + 0;          // 18432
    p.ssrc   = ws + 18432;      // 6144
    p.sdst   = ws + 24576;      // 6144
    p.zseg   = ws + 30720;      // 6144
    p.mkey   = (u32*)(ws + 36864); // 6144
    p.agg    = ws + 43008;      // 18432
    p.ebuf   = ws + 61440;      // 202752
    p.qkv    = ws + 264192;     // 55296
    p.qkv2   = ws + 319488;     // 55296
    p.h2     = ws + 374784;     // 18432
    p.h3     = ws + 393216;     // 18432
    p.numden = ws + 411648;     // 36864
    p.a1pre  = ws + 448512;     // 16
    p.a2buf  = ws + 448528;     // 32
    p.sumres = ws + 448560;     // 1
    p.kmaxk  = (u32*)(ws + 448564); // 3
    p.kmink  = (u32*)(ws + 448568); // 3
    p.out    = (float*)d_out;

    k_init<<<1, 64, 0, stream>>>(p);
    for (int l = 0; l < LGAT; ++l) {
        k_gat_node<<<24, 256, 0, stream>>>(p, l);
        k_edge_max<<<792, 256, 0, stream>>>(p);
        k_edge_sum<<<792, 256, 0, stream>>>(p);
    }
    k_qkv<<<24, 256, 0, stream>>>(p);
    k_att_partial<<<dim3(24, 16), 256, 0, stream>>>(p);
    k_att_reduce<<<24, 256, 0, stream>>>(p);
    k_tc_max<<<792, 256, 0, stream>>>(p);
    k_tc_sum<<<792, 256, 0, stream>>>(p);
    k_tc_final<<<24, 256, 0, stream>>>(p);
    k_mlp1<<<24, 256, 0, stream>>>(p);
    k_mlp2<<<1, 64, 0, stream>>>(p);
    k_mlp3<<<24, 256, 0, stream>>>(p);
    k_value<<<1, 1, 0, stream>>>(p);
}

// Round 3
// 301.935 us; speedup vs baseline: 3.0427x; 3.0427x over previous
//
#include <hip/hip_runtime.h>

#define N 6144
#define E 196608
#define EN (E + N)      // 202752
#define LGAT 10

typedef unsigned int u32;

// order-preserving float<->uint for atomicMax/Min on floats (incl. negatives)
__device__ __forceinline__ u32 f2key(float f) {
    u32 u = __float_as_uint(f);
    return (u & 0x80000000u) ? ~u : (u | 0x80000000u);
}
__device__ __forceinline__ float key2f(u32 k) {
    u32 u = (k & 0x80000000u) ? (k & 0x7FFFFFFFu) : ~k;
    return __uint_as_float(u);
}

struct P {
    // fp32 inputs
    const float *x, *mask, *gat_W, *gat_asrc, *gat_adst, *gat_b;
    const float *in_w, *in_b, *out_w, *out_b;
    const float *Wq, *bq, *Wk, *bk, *Wv, *bv, *Wsk, *bsk;
    const float *W1, *b1, *W2, *b2, *W3, *b3, *cW, *cb;
    const int *src, *dst;
    // fp32 workspace
    float *xp, *ssrc, *sdst, *h, *qkv, *qkv2, *h2, *h3, *numden;
    float *a1pre, *a2buf, *sumres;
    u32 *deg, *offs, *cursor, *kmaxk, *kmink;
    int *ssorted;
    float *out;
};

// ---- init: zero degree histogram + small accumulators --------------------
__global__ void k_init(P p) {
    int t = blockIdx.x * 256 + threadIdx.x;
    if (t < N) p.deg[t] = 0u;
    if (t < 3) p.kmaxk[t] = 0u;
    else if (t < 6) p.kmink[t - 3] = 0xFFFFFFFFu;
    else if (t < 22) p.a1pre[t - 6] = 0.f;
    else if (t == 22) p.sumres[0] = 0.f;
}

// ---- CSR build pass 1: histogram of dst ----------------------------------
__global__ void k_hist(P p) {
    int e = blockIdx.x * 256 + threadIdx.x;
    if (e >= EN) return;
    int d = (e < E) ? p.dst[e] : (e - E);
    atomicAdd(&p.deg[d], 1u);
}

// ---- CSR build pass 2: exclusive scan (single block, 256 threads) --------
__global__ void k_scan(P p) {
    __shared__ u32 part[256];
    int t = threadIdx.x;
    u32 loc[24];
    u32 sum = 0;
    #pragma unroll
    for (int i = 0; i < 24; ++i) { loc[i] = sum; sum += p.deg[t * 24 + i]; }
    part[t] = sum;
    __syncthreads();
    for (int o = 1; o < 256; o <<= 1) {
        u32 v = (t >= o) ? part[t - o] : 0u;
        __syncthreads();
        part[t] += v;
        __syncthreads();
    }
    u32 base = (t == 0) ? 0u : part[t - 1];
    #pragma unroll
    for (int i = 0; i < 24; ++i) {
        u32 off = base + loc[i];
        p.offs[t * 24 + i] = off;
        p.cursor[t * 24 + i] = off;
    }
    if (t == 255) p.offs[N] = part[255];
}

// ---- CSR build pass 3: scatter src ids into dst-sorted order -------------
__global__ void k_scatter(P p) {
    int e = blockIdx.x * 256 + threadIdx.x;
    if (e >= EN) return;
    int s = (e < E) ? p.src[e] : (e - E);
    int d = (e < E) ? p.dst[e] : (e - E);
    u32 pos = atomicAdd(&p.cursor[d], 1u);
    p.ssorted[pos] = s;
}

// ---- GAT node kernel: h -> xp, ssrc, sdst --------------------------------
__global__ void k_gat_node(P p, int l) {
    int n = blockIdx.x * 256 + threadIdx.x;
    const float* hp = (l == 0) ? p.x : p.h;
    float h0 = hp[n * 3 + 0], h1 = hp[n * 3 + 1], h2 = hp[n * 3 + 2];
    const float* W = p.gat_W + l * 9;
    float xp0 = h0 * W[0] + h1 * W[3] + h2 * W[6];
    float xp1 = h0 * W[1] + h1 * W[4] + h2 * W[7];
    float xp2 = h0 * W[2] + h1 * W[5] + h2 * W[8];
    p.xp[n * 3 + 0] = xp0; p.xp[n * 3 + 1] = xp1; p.xp[n * 3 + 2] = xp2;
    const float* as = p.gat_asrc + l * 3;
    const float* ad = p.gat_adst + l * 3;
    p.ssrc[n] = xp0 * as[0] + xp1 * as[1] + xp2 * as[2];
    p.sdst[n] = xp0 * ad[0] + xp1 * ad[1] + xp2 * ad[2];
}

// ---- GAT edge kernel: 16 lanes per dst, no atomics -----------------------
// max pass + exp/sum/agg pass in registers, lane 0 writes h (relu if l<9)
__global__ void k_gat_edge(P p, int l) {
    int gid = blockIdx.x * 256 + threadIdx.x;
    int d = gid >> 4;
    int lane = gid & 15;
    u32 beg = p.offs[d], end = p.offs[d + 1];
    float sd = p.sdst[d];
    float mx = -1e30f;
    for (u32 i = beg + lane; i < end; i += 16) {
        float v = p.ssrc[p.ssorted[i]] + sd;
        v = (v >= 0.f) ? v : 0.2f * v;
        mx = fmaxf(mx, v);
    }
    #pragma unroll
    for (int o = 1; o < 16; o <<= 1) mx = fmaxf(mx, __shfl_xor(mx, o));
    float sz = 0.f, s0 = 0.f, s1 = 0.f, s2 = 0.f;
    for (u32 i = beg + lane; i < end; i += 16) {
        int s = p.ssorted[i];
        float v = p.ssrc[s] + sd;
        v = (v >= 0.f) ? v : 0.2f * v;
        float w = __expf(v - mx);
        sz += w;
        s0 += w * p.xp[s * 3 + 0];
        s1 += w * p.xp[s * 3 + 1];
        s2 += w * p.xp[s * 3 + 2];
    }
    #pragma unroll
    for (int o = 1; o < 16; o <<= 1) {
        sz += __shfl_xor(sz, o);
        s0 += __shfl_xor(s0, o);
        s1 += __shfl_xor(s1, o);
        s2 += __shfl_xor(s2, o);
    }
    if (lane == 0) {
        float z = sz + 1e-16f;
        float b0 = p.gat_b[l * 3 + 0], b1 = p.gat_b[l * 3 + 1], b2 = p.gat_b[l * 3 + 2];
        float o0 = s0 / z + b0, o1 = s1 / z + b1, o2 = s2 / z + b2;
        if (l < LGAT - 1) { o0 = fmaxf(o0, 0.f); o1 = fmaxf(o1, 0.f); o2 = fmaxf(o2, 0.f); }
        p.h[d * 3 + 0] = o0; p.h[d * 3 + 1] = o1; p.h[d * 3 + 2] = o2;
    }
}

// ---- qkv projection + k min/max + numden zero ----------------------------
__global__ void k_qkv(P p) {
    int n = blockIdx.x * 256 + threadIdx.x;   // grid exactly covers N
    float h0 = p.h[n * 3 + 0], h1 = p.h[n * 3 + 1], h2 = p.h[n * 3 + 2];
    float kk[3];
    #pragma unroll
    for (int j = 0; j < 9; ++j) {
        float v = h0 * p.in_w[j * 3 + 0] + h1 * p.in_w[j * 3 + 1] +
                  h2 * p.in_w[j * 3 + 2] + p.in_b[j];
        p.qkv[n * 9 + j] = v;
        if (j >= 3 && j < 6) kk[j - 3] = v;
    }
    #pragma unroll
    for (int j = 0; j < 6; ++j) p.numden[n * 6 + j] = 0.f;
    #pragma unroll
    for (int hh = 0; hh < 3; ++hh) {
        float mx = kk[hh], mn = kk[hh];
        #pragma unroll
        for (int o = 32; o; o >>= 1) {
            mx = fmaxf(mx, __shfl_xor(mx, o));
            mn = fminf(mn, __shfl_xor(mn, o));
        }
        if ((threadIdx.x & 63) == 0) {
            atomicMax(&p.kmaxk[hh], f2key(mx));
            atomicMin(&p.kmink[hh], f2key(mn));
        }
    }
}

// ---- MHA: rank-1 attention, chunked over m, exact max via kmax/kmin ------
#define MCH 384   // 6144/16
__global__ void k_att_partial(P p) {
    __shared__ float kv[MCH * 6];
    int tid = threadIdx.x;
    int chunk = blockIdx.y;
    int mbase = chunk * MCH;
    for (int i = tid; i < MCH * 6; i += 256) {
        int mm = i / 6, r = i - mm * 6;       // r 0..2 -> k[h], 3..5 -> v[h]
        kv[i] = p.qkv[(mbase + mm) * 9 + 3 + r];
    }
    __syncthreads();
    int n = blockIdx.x * 256 + tid;
    float q0 = p.qkv[n * 9 + 0], q1 = p.qkv[n * 9 + 1], q2 = p.qkv[n * 9 + 2];
    float kmx0 = key2f(p.kmaxk[0]), kmx1 = key2f(p.kmaxk[1]), kmx2 = key2f(p.kmaxk[2]);
    float kmn0 = key2f(p.kmink[0]), kmn1 = key2f(p.kmink[1]), kmn2 = key2f(p.kmink[2]);
    // exact row max of q*k over ALL m: q>=0 -> q*kmax else q*kmin
    float M0 = (q0 >= 0.f) ? q0 * kmx0 : q0 * kmn0;
    float M1 = (q1 >= 0.f) ? q1 * kmx1 : q1 * kmn1;
    float M2 = (q2 >= 0.f) ? q2 * kmx2 : q2 * kmn2;
    float num0 = 0, den0 = 0, num1 = 0, den1 = 0, num2 = 0, den2 = 0;
    for (int mm = 0; mm < MCH; ++mm) {
        float k0 = kv[mm * 6 + 0], k1 = kv[mm * 6 + 1], k2 = kv[mm * 6 + 2];
        float v0 = kv[mm * 6 + 3], v1 = kv[mm * 6 + 4], v2 = kv[mm * 6 + 5];
        float t0 = __expf(q0 * k0 - M0); den0 += t0; num0 += t0 * v0;
        float t1 = __expf(q1 * k1 - M1); den1 += t1; num1 += t1 * v1;
        float t2 = __expf(q2 * k2 - M2); den2 += t2; num2 += t2 * v2;
    }
    float* nd = p.numden + n * 6;
    atomicAdd(&nd[0], num0); atomicAdd(&nd[1], den0);
    atomicAdd(&nd[2], num1); atomicAdd(&nd[3], den1);
    atomicAdd(&nd[4], num2); atomicAdd(&nd[5], den2);
}

// ---- MHA reduce + out-proj + TC q2/k2/v2 ---------------------------------
__global__ void k_att_reduce(P p) {
    int n = blockIdx.x * 256 + threadIdx.x;
    float o[3];
    #pragma unroll
    for (int hh = 0; hh < 3; ++hh)
        o[hh] = p.numden[n * 6 + hh * 2] / p.numden[n * 6 + hh * 2 + 1];
    float h2v[3];
    #pragma unroll
    for (int c = 0; c < 3; ++c) {
        h2v[c] = p.out_b[c] + o[0] * p.out_w[c * 3 + 0] +
                 o[1] * p.out_w[c * 3 + 1] + o[2] * p.out_w[c * 3 + 2];
        p.h2[n * 3 + c] = h2v[c];
    }
    #pragma unroll
    for (int c = 0; c < 3; ++c) {
        float q2 = p.bq[c] + h2v[0] * p.Wq[c] + h2v[1] * p.Wq[3 + c] + h2v[2] * p.Wq[6 + c];
        float k2 = p.bk[c] + h2v[0] * p.Wk[c] + h2v[1] * p.Wk[3 + c] + h2v[2] * p.Wk[6 + c];
        float v2 = p.bv[c] + h2v[0] * p.Wv[c] + h2v[1] * p.Wv[3 + c] + h2v[2] * p.Wv[6 + c];
        p.qkv2[n * 9 + c] = q2;
        p.qkv2[n * 9 + 3 + c] = k2;
        p.qkv2[n * 9 + 6 + c] = v2;
    }
}

// ---- TC fused edge kernel: 16 lanes per dst, max+sum+skip in one ---------
__global__ void k_tc_edge(P p) {
    int gid = blockIdx.x * 256 + threadIdx.x;
    int d = gid >> 4;
    int lane = gid & 15;
    u32 beg = p.offs[d], end = p.offs[d + 1];
    float q0 = p.qkv2[d * 9 + 0], q1 = p.qkv2[d * 9 + 1], q2 = p.qkv2[d * 9 + 2];
    const float RS3 = 0.57735026919f;
    float mx = -1e30f;
    for (u32 i = beg + lane; i < end; i += 16) {
        int s = p.ssorted[i];
        float lg = (q0 * p.qkv2[s * 9 + 3] + q1 * p.qkv2[s * 9 + 4] +
                    q2 * p.qkv2[s * 9 + 5]) * RS3;
        mx = fmaxf(mx, lg);
    }
    #pragma unroll
    for (int o = 1; o < 16; o <<= 1) mx = fmaxf(mx, __shfl_xor(mx, o));
    float sz = 0.f, s0 = 0.f, s1 = 0.f, s2 = 0.f;
    for (u32 i = beg + lane; i < end; i += 16) {
        int s = p.ssorted[i];
        float lg = (q0 * p.qkv2[s * 9 + 3] + q1 * p.qkv2[s * 9 + 4] +
                    q2 * p.qkv2[s * 9 + 5]) * RS3;
        float w = __expf(lg - mx);
        sz += w;
        s0 += w * p.qkv2[s * 9 + 6];
        s1 += w * p.qkv2[s * 9 + 7];
        s2 += w * p.qkv2[s * 9 + 8];
    }
    #pragma unroll
    for (int o = 1; o < 16; o <<= 1) {
        sz += __shfl_xor(sz, o);
        s0 += __shfl_xor(s0, o);
        s1 += __shfl_xor(s1, o);
        s2 += __shfl_xor(s2, o);
    }
    if (lane == 0) {
        float z = sz + 1e-16f;
        float h0 = p.h2[d * 3 + 0], h1 = p.h2[d * 3 + 1], h2 = p.h2[d * 3 + 2];
        #pragma unroll
        for (int c = 0; c < 3; ++c) {
            float agg = (c == 0 ? s0 : (c == 1 ? s1 : s2)) / z;
            p.h3[d * 3 + c] = agg + p.bsk[c] +
                h0 * p.Wsk[c] + h1 * p.Wsk[3 + c] + h2 * p.Wsk[6 + c];
        }
    }
}

// ---- MLP stage 1: flat(18432) @ W1(18432x16) -> a1pre[16] ----------------
__global__ void k_mlp1(P p) {
    int g = blockIdx.x * 256 + threadIdx.x;   // 6144 threads
    float acc[16];
    #pragma unroll
    for (int j = 0; j < 16; ++j) acc[j] = 0.f;
    for (int i = g; i < 3 * N; i += 6144) {
        float f = p.h3[i];
        const float* w = p.W1 + (size_t)i * 16;
        #pragma unroll
        for (int j = 0; j < 16; ++j) acc[j] += f * w[j];
    }
    #pragma unroll
    for (int o = 32; o; o >>= 1)
        #pragma unroll
        for (int j = 0; j < 16; ++j) acc[j] += __shfl_xor(acc[j], o);
    if ((threadIdx.x & 63) == 0)
        #pragma unroll
        for (int j = 0; j < 16; ++j) atomicAdd(&p.a1pre[j], acc[j]);
}

// ---- MLP stage 2: a1 -> a2 (tiny) ----------------------------------------
__global__ void k_mlp2(P p) {
    __shared__ float a1[16];
    int t = threadIdx.x;
    if (t < 16) a1[t] = fmaxf(p.a1pre[t] + p.b1[t], 0.f);
    __syncthreads();
    if (t < 32) {
        float acc = p.b2[t];
        #pragma unroll
        for (int i = 0; i < 16; ++i) acc += a1[i] * p.W2[i * 32 + t];
        p.a2buf[t] = fmaxf(acc, 0.f);
    }
}

// ---- MLP stage 3: results = a2 @ W3 + b3; out, mean ----------------------
__global__ void k_mlp3(P p) {
    __shared__ float a2[32];
    if (threadIdx.x < 32) a2[threadIdx.x] = p.a2buf[threadIdx.x];
    __syncthreads();
    int n = blockIdx.x * 256 + threadIdx.x;
    float acc = p.b3[n];
    #pragma unroll
    for (int j = 0; j < 32; ++j) acc += a2[j] * p.W3[(size_t)j * N + n];
    p.out[n] = acc * p.mask[n];
    float s = acc;
    #pragma unroll
    for (int o = 32; o; o >>= 1) s += __shfl_xor(s, o);
    if ((threadIdx.x & 63) == 0) atomicAdd(p.sumres, s);
}

// ---- value ---------------------------------------------------------------
__global__ void k_value(P p) {
    p.out[N] = p.cW[0] * (p.sumres[0] / (float)N) + p.cb[0];
}

extern "C" void kernel_launch(void* const* d_in, const int* in_sizes, int n_in,
                              void* d_out, int out_size, void* d_ws, size_t ws_size,
                              hipStream_t stream) {
    P p;
    p.x      = (const float*)d_in[0];
    p.mask   = (const float*)d_in[1];
    const int* ei = (const int*)d_in[2];
    p.src = ei; p.dst = ei + E;
    p.gat_W  = (const float*)d_in[3];
    p.gat_asrc = (const float*)d_in[4];
    p.gat_adst = (const float*)d_in[5];
    p.gat_b  = (const float*)d_in[6];
    p.in_w   = (const float*)d_in[7];
    p.in_b   = (const float*)d_in[8];
    p.out_w  = (const float*)d_in[9];
    p.out_b  = (const float*)d_in[10];
    p.Wq = (const float*)d_in[11]; p.bq = (const float*)d_in[12];
    p.Wk = (const float*)d_in[13]; p.bk = (const float*)d_in[14];
    p.Wv = (const float*)d_in[15]; p.bv = (const float*)d_in[16];
    p.Wsk = (const float*)d_in[17]; p.bsk = (const float*)d_in[18];
    p.W1 = (const float*)d_in[19]; p.b1 = (const float*)d_in[20];
    p.W2 = (const float*)d_in[21]; p.b2 = (const float*)d_in[22];
    p.W3 = (const float*)d_in[23]; p.b3 = (const float*)d_in[24];
    p.cW = (const float*)d_in[25]; p.cb = (const float*)d_in[26];

    float* ws = (float*)d_ws;
    p.xp      = ws + 0;          // 18432
    p.ssrc    = ws + 18432;      // 6144
    p.sdst    = ws + 24576;      // 6144
    p.h       = ws + 30720;      // 18432
    p.qkv     = ws + 49152;      // 55296
    p.qkv2    = ws + 104448;     // 55296
    p.h2      = ws + 159744;     // 18432
    p.h3      = ws + 178176;     // 18432
    p.numden  = ws + 196608;     // 36864
    p.deg     = (u32*)(ws + 233472);   // 6144
    p.offs    = (u32*)(ws + 239616);   // 6145
    p.cursor  = (u32*)(ws + 245761);   // 6144
    p.ssorted = (int*)(ws + 251905);   // 202752
    p.a1pre   = ws + 454657;     // 16
    p.a2buf   = ws + 454673;     // 32
    p.sumres  = ws + 454705;     // 1
    p.kmaxk   = (u32*)(ws + 454706);   // 3
    p.kmink   = (u32*)(ws + 454709);   // 3
    p.out     = (float*)d_out;

    // CSR build (once per launch)
    k_init<<<24, 256, 0, stream>>>(p);
    k_hist<<<792, 256, 0, stream>>>(p);
    k_scan<<<1, 256, 0, stream>>>(p);
    k_scatter<<<792, 256, 0, stream>>>(p);
    // GAT stack
    for (int l = 0; l < LGAT; ++l) {
        k_gat_node<<<24, 256, 0, stream>>>(p, l);
        k_gat_edge<<<384, 256, 0, stream>>>(p, l);
    }
    // MHA
    k_qkv<<<24, 256, 0, stream>>>(p);
    k_att_partial<<<dim3(24, 16), 256, 0, stream>>>(p);
    k_att_reduce<<<24, 256, 0, stream>>>(p);
    // TC
    k_tc_edge<<<384, 256, 0, stream>>>(p);
    // MLP
    k_mlp1<<<24, 256, 0, stream>>>(p);
    k_mlp2<<<1, 64, 0, stream>>>(p);
    k_mlp3<<<24, 256, 0, stream>>>(p);
    k_value<<<1, 1, 0, stream>>>(p);
}